// Round 1
// baseline (164.791 us; speedup 1.0000x reference)
//
#include <hip/hip_runtime.h>
#include <math.h>

#define LL 1024
#define DD 640
#define KK 32
#define MM 64
#define THRESH 0.2f

// workspace layout (floats)
#define NPROJ_OFF 0                      // [L][M] node_proj + b_edge
#define W0_OFF    (LL * MM)              // 64  : W_edge[0][:]
#define W1_OFF    (W0_OFF + MM)          // 64  : W_edge[1][:]
#define WR_OFF    (W1_OFF + MM)          // 32*64 : W_edge[2+k][m]
#define MU_OFF    (WR_OFF + KK * MM)     // 32
#define IS_OFF    (MU_OFF + KK)          // 32 : 1/(2*sigma^2)

__global__ __launch_bounds__(64) void prep_kernel(
    const float* __restrict__ S, const float* __restrict__ rbf_mu,
    const float* __restrict__ rbf_sigma, const float* __restrict__ W_edge,
    const float* __restrict__ b_edge, const float* __restrict__ W_node,
    float* __restrict__ ws)
{
    const int b = blockIdx.x;
    const int t = threadIdx.x;
    if (b < LL / 2) {
        // node_proj for rows 2b, 2b+1 ; lane t = output feature m
        const int j0 = b * 2;
        float acc0 = b_edge[t];
        float acc1 = acc0;
        const float* s0 = S + (size_t)j0 * DD;
        const float* s1 = s0 + DD;
        #pragma unroll 4
        for (int d = 0; d < DD; ++d) {
            float w = W_node[d * MM + t];
            acc0 = fmaf(s0[d], w, acc0);
            acc1 = fmaf(s1[d], w, acc1);
        }
        ws[NPROJ_OFF + (size_t)j0 * MM + t]       = acc0;
        ws[NPROJ_OFF + (size_t)(j0 + 1) * MM + t] = acc1;
    } else {
        // constants repack
        ws[W0_OFF + t] = W_edge[t];           // row 0
        ws[W1_OFF + t] = W_edge[MM + t];      // row 1
        for (int idx = t; idx < KK * MM; idx += 64)
            ws[WR_OFF + idx] = W_edge[2 * MM + idx];
        if (t < KK) {
            ws[MU_OFF + t] = rbf_mu[t];
            float s = rbf_sigma[t];
            ws[IS_OFF + t] = 1.0f / (2.0f * s * s);
        }
    }
}

__global__ __launch_bounds__(256, 2) void edge_kernel(
    const float* __restrict__ P, const float* __restrict__ xyz,
    const float* __restrict__ w_out, const float* __restrict__ ws,
    float* __restrict__ out)
{
    const int tid = threadIdx.x;
    __shared__ float sred[4][3];

    const float* __restrict__ nproj = ws + NPROJ_OFF;
    const float* __restrict__ W0 = ws + W0_OFF;
    const float* __restrict__ W1 = ws + W1_OFF;
    const float* __restrict__ Wr = ws + WR_OFF;
    const float* __restrict__ mu = ws + MU_OFF;
    const float* __restrict__ is2 = ws + IS_OFF;

    int rows[2];
    rows[0] = (int)blockIdx.x;
    rows[1] = (LL - 1) - (int)blockIdx.x;

    for (int rr = 0; rr < 2; ++rr) {
        const int i = rows[rr];
        const float xi0 = xyz[i * 3 + 0];
        const float xi1 = xyz[i * 3 + 1];
        const float xi2 = xyz[i * 3 + 2];
        float ax = 0.f, ay = 0.f, az = 0.f;
        const int len = (LL - 1) - i;   // j in [i+1, L-1], jo = j-(i+1) in [0,len)

        for (int base = 0; base < len; base += 256) {
            const int jo = base + tid;
            const bool valid = jo < len;
            const int jc = valid ? (i + 1 + jo) : (LL - 1);

            const float p = P[(size_t)i * LL + jc];
            const bool backbone = (jo == 0);
            const bool contact  = (jo >= 2) && (p > THRESH);   // j > i+2
            const bool msk = valid && (backbone || contact);
            const float etype = contact ? 1.0f : 0.0f;
            const float pij   = backbone ? 1.0f : p;

            const float rx = xyz[jc * 3 + 0] - xi0;
            const float ry = xyz[jc * 3 + 1] - xi1;
            const float rz = xyz[jc * 3 + 2] - xi2;
            const float d = sqrtf(fmaf(rx, rx, fmaf(ry, ry, fmaf(rz, rz, 1e-12f))));

            // msg init: node_proj[j] (+b_edge already) + etype*W0 + pij*W1
            float msg[MM];
            const float4* np4 = (const float4*)(nproj + (size_t)jc * MM);
            #pragma unroll
            for (int q = 0; q < 16; ++q) {
                float4 v = np4[q];
                float4 a = ((const float4*)W0)[q];   // uniform -> s_load
                float4 b = ((const float4*)W1)[q];   // uniform -> s_load
                msg[4 * q + 0] = fmaf(etype, a.x, fmaf(pij, b.x, v.x));
                msg[4 * q + 1] = fmaf(etype, a.y, fmaf(pij, b.y, v.y));
                msg[4 * q + 2] = fmaf(etype, a.z, fmaf(pij, b.z, v.z));
                msg[4 * q + 3] = fmaf(etype, a.w, fmaf(pij, b.w, v.w));
            }

            // rank-32 RBF part: msg += rbf_k * Wr[k][:]
            #pragma unroll 2
            for (int k = 0; k < KK; ++k) {
                const float t0 = d - mu[k];                 // uniform s_load
                const float r = __expf(-(t0 * t0) * is2[k]); // uniform s_load
                const float4* w4 = (const float4*)(Wr + k * MM);
                #pragma unroll
                for (int q = 0; q < 16; ++q) {
                    float4 w = w4[q];                       // uniform -> s_load
                    msg[4 * q + 0] = fmaf(r, w.x, msg[4 * q + 0]);
                    msg[4 * q + 1] = fmaf(r, w.y, msg[4 * q + 1]);
                    msg[4 * q + 2] = fmaf(r, w.z, msg[4 * q + 2]);
                    msg[4 * q + 3] = fmaf(r, w.w, msg[4 * q + 3]);
                }
            }

            // relu + dot w_out
            float g0 = 0.f, g1 = 0.f, g2 = 0.f, g3 = 0.f;
            #pragma unroll
            for (int q = 0; q < 16; ++q) {
                float4 w = ((const float4*)w_out)[q];       // uniform -> s_load
                g0 = fmaf(fmaxf(msg[4 * q + 0], 0.f), w.x, g0);
                g1 = fmaf(fmaxf(msg[4 * q + 1], 0.f), w.y, g1);
                g2 = fmaf(fmaxf(msg[4 * q + 2], 0.f), w.z, g2);
                g3 = fmaf(fmaxf(msg[4 * q + 3], 0.f), w.w, g3);
            }
            const float gdot = (g0 + g1) + (g2 + g3);
            const float gate = msk ? (1.0f / (1.0f + __expf(-gdot))) : 0.0f;

            ax = fmaf(gate, rx, ax);
            ay = fmaf(gate, ry, ay);
            az = fmaf(gate, rz, az);
        }

        // block reduction: wave shuffle then LDS across 4 waves
        #pragma unroll
        for (int off = 32; off > 0; off >>= 1) {
            ax += __shfl_down(ax, off, 64);
            ay += __shfl_down(ay, off, 64);
            az += __shfl_down(az, off, 64);
        }
        const int wave = tid >> 6;
        if ((tid & 63) == 0) {
            sred[wave][0] = ax; sred[wave][1] = ay; sred[wave][2] = az;
        }
        __syncthreads();
        if (tid == 0) {
            float tx = (sred[0][0] + sred[1][0]) + (sred[2][0] + sred[3][0]);
            float ty = (sred[0][1] + sred[1][1]) + (sred[2][1] + sred[3][1]);
            float tz = (sred[0][2] + sred[1][2]) + (sred[2][2] + sred[3][2]);
            out[i * 3 + 0] = xi0 + tx;
            out[i * 3 + 1] = xi1 + ty;
            out[i * 3 + 2] = xi2 + tz;
        }
        __syncthreads();   // protect sred before next row
    }
}

extern "C" void kernel_launch(void* const* d_in, const int* in_sizes, int n_in,
                              void* d_out, int out_size, void* d_ws, size_t ws_size,
                              hipStream_t stream) {
    const float* S         = (const float*)d_in[0];
    const float* P         = (const float*)d_in[1];
    const float* xyz       = (const float*)d_in[2];
    const float* rbf_mu    = (const float*)d_in[3];
    const float* rbf_sigma = (const float*)d_in[4];
    const float* W_edge    = (const float*)d_in[5];
    const float* b_edge    = (const float*)d_in[6];
    const float* W_node    = (const float*)d_in[7];
    const float* w_out     = (const float*)d_in[8];
    float* out = (float*)d_out;
    float* ws  = (float*)d_ws;

    // 512 node_proj blocks (2 rows each) + 1 constants block
    prep_kernel<<<LL / 2 + 1, 64, 0, stream>>>(S, rbf_mu, rbf_sigma, W_edge,
                                               b_edge, W_node, ws);
    // block b handles rows {b, 1023-b} for load balance
    edge_kernel<<<LL / 2, 256, 0, stream>>>(P, xyz, w_out, ws, out);
}

// Round 2
// 104.176 us; speedup vs baseline: 1.5819x; 1.5819x over previous
//
#include <hip/hip_runtime.h>
#include <math.h>

#define LL 1024
#define DD 640
#define KK 32
#define MM 64
#define THRESH 0.2f

// workspace layout (float units)
#define NPROJ_OFF 0                       // [1024][64] fp32 node_proj (+b_edge)
#define WRT_OFF   (LL * MM)               // ushort[64][32]: bf16 W_edge[2+k][m] transposed (m-major)
#define W0_OFF    (WRT_OFF + 1024)        // 64 fp32 : W_edge[0][:]
#define W1_OFF    (W0_OFF + MM)           // 64 fp32 : W_edge[1][:]
#define MU_OFF    (W1_OFF + MM)           // 32 fp32
#define NIS2_OFF  (MU_OFF + KK)           // 32 fp32 : -1/(2*sigma^2)

typedef float f32x4_t __attribute__((ext_vector_type(4)));
typedef short bf16x8_t __attribute__((ext_vector_type(8)));

union FragU { unsigned int u[4]; bf16x8_t v; };

// pack two fp32 into one VGPR of two bf16 (truncation via v_perm_b32; rbf/pij
// magnitudes <=1, 0.4% max err -- far under threshold)
__device__ __forceinline__ unsigned int pack_bf(float hi, float lo) {
    return __builtin_amdgcn_perm(__float_as_uint(hi), __float_as_uint(lo), 0x07060302u);
}

__global__ __launch_bounds__(256) void prep_kernel(
    const float* __restrict__ S, const float* __restrict__ rbf_mu,
    const float* __restrict__ rbf_sigma, const float* __restrict__ W_edge,
    const float* __restrict__ b_edge, const float* __restrict__ W_node,
    float* __restrict__ ws)
{
    __shared__ float red[4][2][64];
    const int b = blockIdx.x;
    const int t = threadIdx.x;
    if (b < LL / 2) {
        // node_proj GEMM: 2 rows per block, thread t: m = t&63, k-chunk c = t>>6
        const int m = t & 63;
        const int c = t >> 6;
        const int r0 = b * 2;
        float a0 = 0.f, a1 = 0.f;
        const int d0 = c * 160;
        #pragma unroll 2
        for (int dd = d0; dd < d0 + 160; dd += 4) {
            const float4 s0 = *(const float4*)(S + (size_t)r0 * DD + dd);
            const float4 s1 = *(const float4*)(S + (size_t)(r0 + 1) * DD + dd);
            const float w0 = W_node[(dd + 0) * MM + m];
            const float w1 = W_node[(dd + 1) * MM + m];
            const float w2 = W_node[(dd + 2) * MM + m];
            const float w3 = W_node[(dd + 3) * MM + m];
            a0 = fmaf(s0.x, w0, a0); a0 = fmaf(s0.y, w1, a0);
            a0 = fmaf(s0.z, w2, a0); a0 = fmaf(s0.w, w3, a0);
            a1 = fmaf(s1.x, w0, a1); a1 = fmaf(s1.y, w1, a1);
            a1 = fmaf(s1.z, w2, a1); a1 = fmaf(s1.w, w3, a1);
        }
        red[c][0][m] = a0;
        red[c][1][m] = a1;
        __syncthreads();
        if (t < 64) {
            const float be = b_edge[t];
            const float v0 = ((red[0][0][t] + red[1][0][t]) + (red[2][0][t] + red[3][0][t])) + be;
            const float v1 = ((red[0][1][t] + red[1][1][t]) + (red[2][1][t] + red[3][1][t])) + be;
            ws[NPROJ_OFF + (size_t)r0 * MM + t]       = v0;
            ws[NPROJ_OFF + (size_t)(r0 + 1) * MM + t] = v1;
        }
    } else {
        // constants repack
        unsigned short* wrt = (unsigned short*)(ws + WRT_OFF);
        if (t < MM) {
            ws[W0_OFF + t] = W_edge[t];
            ws[W1_OFF + t] = W_edge[MM + t];
        }
        if (t < KK) {
            ws[MU_OFF + t] = rbf_mu[t];
            const float s = rbf_sigma[t];
            ws[NIS2_OFF + t] = -1.0f / (2.0f * s * s);
        }
        for (int idx = t; idx < KK * MM; idx += 256) {
            const int m = idx >> 5, k = idx & 31;
            unsigned int u = __float_as_uint(W_edge[(2 + k) * MM + m]);
            u = (u + 0x7fffu + ((u >> 16) & 1u)) >> 16;   // RNE to bf16
            wrt[idx] = (unsigned short)u;
        }
    }
}

__global__ __launch_bounds__(256, 2) void edge_kernel(
    const float* __restrict__ P, const float* __restrict__ xyz,
    const float* __restrict__ w_out, const float* __restrict__ ws,
    float* __restrict__ out)
{
    const int tid  = threadIdx.x;
    const int lane = tid & 63;
    const int wave = tid >> 6;
    const int quad = lane >> 4;
    const int col  = lane & 15;
    __shared__ float sred[4][3];

    const float* __restrict__ nproj = ws + NPROJ_OFF;
    const unsigned short* __restrict__ wrt = (const unsigned short*)(ws + WRT_OFF);

    // ---- persistent register fragments (loaded once) ----
    // A frags: A[m = mt*16+col][k = quad*8+j] = W_edge_rbf[k][m], bf16
    FragU ar[4], a2[4];
    float wv[4][4];     // w_out[mt*16 + quad*4 + r]
    float muj[8], nis2[8];
    #pragma unroll
    for (int mt = 0; mt < 4; ++mt) {
        const uint4 w = *(const uint4*)(wrt + (mt * 16 + col) * KK + quad * 8);
        ar[mt].u[0] = w.x; ar[mt].u[1] = w.y; ar[mt].u[2] = w.z; ar[mt].u[3] = w.w;
        const float w0 = ws[W0_OFF + mt * 16 + col];
        const float w1 = ws[W1_OFF + mt * 16 + col];
        a2[mt].u[0] = (quad == 0) ? pack_bf(w1, w0) : 0u;   // k=0 -> W0, k=1 -> W1
        a2[mt].u[1] = 0u; a2[mt].u[2] = 0u; a2[mt].u[3] = 0u;
        const float4 wo = *(const float4*)(w_out + mt * 16 + quad * 4);
        wv[mt][0] = wo.x; wv[mt][1] = wo.y; wv[mt][2] = wo.z; wv[mt][3] = wo.w;
    }
    #pragma unroll
    for (int j = 0; j < 8; ++j) {
        muj[j]  = ws[MU_OFF + quad * 8 + j];
        nis2[j] = ws[NIS2_OFF + quad * 8 + j];
    }

    int rows[2];
    rows[0] = (int)blockIdx.x;
    rows[1] = (LL - 1) - (int)blockIdx.x;

    for (int rr = 0; rr < 2; ++rr) {
        const int i = rows[rr];
        const float xi0 = xyz[i * 3 + 0];
        const float xi1 = xyz[i * 3 + 1];
        const float xi2 = xyz[i * 3 + 2];
        float ax = 0.f, ay = 0.f, az = 0.f;
        const int len = (LL - 1) - i;          // jo = j-(i+1) in [0,len)

        for (int base = wave * 64; base < len; base += 256) {
            const int jo = base + lane;        // this lane's own edge
            const bool valid = jo < len;
            const int jc = valid ? (i + 1 + jo) : (LL - 1);
            const float p_own = P[(size_t)i * LL + jc];
            const float rx = xyz[jc * 3 + 0] - xi0;
            const float ry = xyz[jc * 3 + 1] - xi1;
            const float rz = xyz[jc * 3 + 2] - xi2;
            const float d_own = sqrtf(fmaf(rx, rx, fmaf(ry, ry, fmaf(rz, rz, 1e-12f))));
            const bool msk = valid && ((jo == 0) || ((jo >= 2) && (p_own > THRESH)));

            float res[4];
            #pragma unroll
            for (int ct = 0; ct < 4; ++ct) {
                const int src = ct * 16 + col;           // lane holding column edge's d,p
                const float d_t = __shfl(d_own, src, 64);
                const float p_t = __shfl(p_own, src, 64);
                const int jo_t = base + src;
                const float et = ((jo_t >= 2) && (p_t > THRESH)) ? 1.0f : 0.0f;
                const float pj = (jo_t == 0) ? 1.0f : p_t;

                // B frag: rbf[k = quad*8+j][edge col]
                float r[8];
                #pragma unroll
                for (int j = 0; j < 8; ++j) {
                    const float t0 = d_t - muj[j];
                    r[j] = __expf(t0 * t0 * nis2[j]);
                }
                FragU bf;
                bf.u[0] = pack_bf(r[1], r[0]); bf.u[1] = pack_bf(r[3], r[2]);
                bf.u[2] = pack_bf(r[5], r[4]); bf.u[3] = pack_bf(r[7], r[6]);
                FragU b2;
                b2.u[0] = (quad == 0) ? pack_bf(pj, et) : 0u;  // k=0 etype, k=1 pij
                b2.u[1] = 0u; b2.u[2] = 0u; b2.u[3] = 0u;

                const int jc_t = (jo_t < len) ? (i + 1 + jo_t) : (LL - 1);
                const float* npr = nproj + (size_t)jc_t * MM;

                float g = 0.0f;
                #pragma unroll
                for (int mt = 0; mt < 4; ++mt) {
                    f32x4_t c0 = *(const f32x4_t*)(npr + mt * 16 + quad * 4);
                    c0 = __builtin_amdgcn_mfma_f32_16x16x32_bf16(ar[mt].v, bf.v, c0, 0, 0, 0);
                    c0 = __builtin_amdgcn_mfma_f32_16x16x32_bf16(a2[mt].v, b2.v, c0, 0, 0, 0);
                    g = fmaf(fmaxf(c0[0], 0.f), wv[mt][0], g);
                    g = fmaf(fmaxf(c0[1], 0.f), wv[mt][1], g);
                    g = fmaf(fmaxf(c0[2], 0.f), wv[mt][2], g);
                    g = fmaf(fmaxf(c0[3], 0.f), wv[mt][3], g);
                }
                // sum the 4 quad-partials -> every lane holds gdot of edge ct*16+(lane&15)
                g += __shfl_xor(g, 16, 64);
                g += __shfl_xor(g, 32, 64);
                res[ct] = g;
            }
            // lane l's own edge (base+l) lives in res[quad]
            float gd = res[0];
            gd = (quad == 1) ? res[1] : gd;
            gd = (quad == 2) ? res[2] : gd;
            gd = (quad == 3) ? res[3] : gd;
            const float gate = msk ? (1.0f / (1.0f + __expf(-gd))) : 0.0f;
            ax = fmaf(gate, rx, ax);
            ay = fmaf(gate, ry, ay);
            az = fmaf(gate, rz, az);
        }

        // reduce 64 lanes, then 4 waves
        #pragma unroll
        for (int off = 32; off > 0; off >>= 1) {
            ax += __shfl_down(ax, off, 64);
            ay += __shfl_down(ay, off, 64);
            az += __shfl_down(az, off, 64);
        }
        if (lane == 0) {
            sred[wave][0] = ax; sred[wave][1] = ay; sred[wave][2] = az;
        }
        __syncthreads();
        if (tid == 0) {
            const float tx = (sred[0][0] + sred[1][0]) + (sred[2][0] + sred[3][0]);
            const float ty = (sred[0][1] + sred[1][1]) + (sred[2][1] + sred[3][1]);
            const float tz = (sred[0][2] + sred[1][2]) + (sred[2][2] + sred[3][2]);
            out[i * 3 + 0] = xi0 + tx;
            out[i * 3 + 1] = xi1 + ty;
            out[i * 3 + 2] = xi2 + tz;
        }
        __syncthreads();
    }
}

extern "C" void kernel_launch(void* const* d_in, const int* in_sizes, int n_in,
                              void* d_out, int out_size, void* d_ws, size_t ws_size,
                              hipStream_t stream) {
    const float* S         = (const float*)d_in[0];
    const float* P         = (const float*)d_in[1];
    const float* xyz       = (const float*)d_in[2];
    const float* rbf_mu    = (const float*)d_in[3];
    const float* rbf_sigma = (const float*)d_in[4];
    const float* W_edge    = (const float*)d_in[5];
    const float* b_edge    = (const float*)d_in[6];
    const float* W_node    = (const float*)d_in[7];
    const float* w_out     = (const float*)d_in[8];
    float* out = (float*)d_out;
    float* ws  = (float*)d_ws;

    prep_kernel<<<LL / 2 + 1, 256, 0, stream>>>(S, rbf_mu, rbf_sigma, W_edge,
                                                b_edge, W_node, ws);
    edge_kernel<<<LL / 2, 256, 0, stream>>>(P, xyz, w_out, ws, out);
}

// Round 3
// 102.515 us; speedup vs baseline: 1.6075x; 1.0162x over previous
//
#include <hip/hip_runtime.h>
#include <math.h>

#define LL 1024
#define DD 640
#define KK 32
#define MM 64
#define THRESH 0.2f

// workspace layout (float units)
#define NPROJ_OFF 0                       // [1024][64] fp32 node_proj (+b_edge)
#define WRT_OFF   (LL * MM)               // ushort[64][32]: bf16 W_edge[2+k][m] transposed (m-major)
#define W0_OFF    (WRT_OFF + 1024)        // 64 fp32 : W_edge[0][:]
#define W1_OFF    (W0_OFF + MM)           // 64 fp32 : W_edge[1][:]
#define MU_OFF    (W1_OFF + MM)           // 32 fp32
#define NIS2_OFF  (MU_OFF + KK)           // 32 fp32 : -1/(2*sigma^2)

typedef float f32x4_t __attribute__((ext_vector_type(4)));
typedef short bf16x8_t __attribute__((ext_vector_type(8)));

union FragU { unsigned int u[4]; bf16x8_t v; };

// pack two fp32 into one VGPR of two bf16 (truncation; rbf magnitudes <=1)
__device__ __forceinline__ unsigned int pack_bf(float hi, float lo) {
    return __builtin_amdgcn_perm(__float_as_uint(hi), __float_as_uint(lo), 0x07060302u);
}

__global__ __launch_bounds__(256) void prep_kernel(
    const float* __restrict__ S, const float* __restrict__ rbf_mu,
    const float* __restrict__ rbf_sigma, const float* __restrict__ W_edge,
    const float* __restrict__ b_edge, const float* __restrict__ W_node,
    float* __restrict__ ws)
{
    __shared__ float red[4][2][64];
    const int b = blockIdx.x;
    const int t = threadIdx.x;
    if (b < LL / 2) {
        // node_proj GEMM: 2 rows per block, thread t: m = t&63, k-chunk c = t>>6
        const int m = t & 63;
        const int c = t >> 6;
        const int r0 = b * 2;
        float a0 = 0.f, a1 = 0.f;
        const int d0 = c * 160;
        #pragma unroll 4
        for (int dd = d0; dd < d0 + 160; dd += 4) {
            const float4 s0 = *(const float4*)(S + (size_t)r0 * DD + dd);
            const float4 s1 = *(const float4*)(S + (size_t)(r0 + 1) * DD + dd);
            const float w0 = W_node[(dd + 0) * MM + m];
            const float w1 = W_node[(dd + 1) * MM + m];
            const float w2 = W_node[(dd + 2) * MM + m];
            const float w3 = W_node[(dd + 3) * MM + m];
            a0 = fmaf(s0.x, w0, a0); a0 = fmaf(s0.y, w1, a0);
            a0 = fmaf(s0.z, w2, a0); a0 = fmaf(s0.w, w3, a0);
            a1 = fmaf(s1.x, w0, a1); a1 = fmaf(s1.y, w1, a1);
            a1 = fmaf(s1.z, w2, a1); a1 = fmaf(s1.w, w3, a1);
        }
        red[c][0][m] = a0;
        red[c][1][m] = a1;
        __syncthreads();
        if (t < 64) {
            const float be = b_edge[t];
            const float v0 = ((red[0][0][t] + red[1][0][t]) + (red[2][0][t] + red[3][0][t])) + be;
            const float v1 = ((red[0][1][t] + red[1][1][t]) + (red[2][1][t] + red[3][1][t])) + be;
            ws[NPROJ_OFF + (size_t)r0 * MM + t]       = v0;
            ws[NPROJ_OFF + (size_t)(r0 + 1) * MM + t] = v1;
        }
    } else {
        // constants repack
        unsigned short* wrt = (unsigned short*)(ws + WRT_OFF);
        if (t < MM) {
            ws[W0_OFF + t] = W_edge[t];
            ws[W1_OFF + t] = W_edge[MM + t];
        }
        if (t < KK) {
            ws[MU_OFF + t] = rbf_mu[t];
            const float s = rbf_sigma[t];
            ws[NIS2_OFF + t] = -1.0f / (2.0f * s * s);
        }
        for (int idx = t; idx < KK * MM; idx += 256) {
            const int m = idx >> 5, k = idx & 31;
            unsigned int u = __float_as_uint(W_edge[(2 + k) * MM + m]);
            u = (u + 0x7fffu + ((u >> 16) & 1u)) >> 16;   // RNE to bf16
            wrt[idx] = (unsigned short)u;
        }
    }
}

__global__ __launch_bounds__(512, 4) void edge_kernel(
    const float* __restrict__ P, const float* __restrict__ xyz,
    const float* __restrict__ w_out, const float* __restrict__ ws,
    float* __restrict__ out)
{
    const int tid  = threadIdx.x;
    const int lane = tid & 63;
    const int wave = tid >> 6;
    const int quad = lane >> 4;
    const int col  = lane & 15;
    __shared__ float sred[8][3];

    const float* __restrict__ nproj = ws + NPROJ_OFF;
    const unsigned short* __restrict__ wrt = (const unsigned short*)(ws + WRT_OFF);

    // ---- persistent register fragments (loaded once) ----
    // A frags: A[m = mt*16+col][k = quad*8+j] = W_edge_rbf[k][m], bf16
    FragU ar[4];
    f32x4_t w0q[4], w1q[4], wv[4];   // W0/W1/w_out at m = mt*16 + quad*4 + r (C-layout)
    float muj[8], nis2[8];
    #pragma unroll
    for (int mt = 0; mt < 4; ++mt) {
        const uint4 w = *(const uint4*)(wrt + (mt * 16 + col) * KK + quad * 8);
        ar[mt].u[0] = w.x; ar[mt].u[1] = w.y; ar[mt].u[2] = w.z; ar[mt].u[3] = w.w;
        w0q[mt] = *(const f32x4_t*)(ws + W0_OFF + mt * 16 + quad * 4);
        w1q[mt] = *(const f32x4_t*)(ws + W1_OFF + mt * 16 + quad * 4);
        wv[mt]  = *(const f32x4_t*)(w_out + mt * 16 + quad * 4);
    }
    #pragma unroll
    for (int j = 0; j < 8; ++j) {
        muj[j]  = ws[MU_OFF + quad * 8 + j];
        nis2[j] = ws[NIS2_OFF + quad * 8 + j];
    }

    int rows[2];
    rows[0] = (int)blockIdx.x;
    rows[1] = (LL - 1) - (int)blockIdx.x;

    for (int rr = 0; rr < 2; ++rr) {
        const int i = rows[rr];
        const float xi0 = xyz[i * 3 + 0];
        const float xi1 = xyz[i * 3 + 1];
        const float xi2 = xyz[i * 3 + 2];
        float ax = 0.f, ay = 0.f, az = 0.f;
        const int len = (LL - 1) - i;          // jo = j-(i+1) in [0,len)

        for (int base = wave * 64; base < len; base += 512) {
            // own edge (for mask + gated accumulation)
            const int jo = base + lane;
            const bool valid = jo < len;
            const int jc = valid ? (i + 1 + jo) : (LL - 1);
            const float p_own = P[(size_t)i * LL + jc];
            const float rx = xyz[jc * 3 + 0] - xi0;
            const float ry = xyz[jc * 3 + 1] - xi1;
            const float rz = xyz[jc * 3 + 2] - xi2;
            const bool msk = valid && ((jo == 0) || ((jo >= 2) && (p_own > THRESH)));

            float res[4];
            #pragma unroll
            for (int ct = 0; ct < 4; ++ct) {
                // column edge n = ct*16 + col: compute its d,p directly (L1 broadcast,
                // no shfl at the head of the dependency chain)
                const int jo_n = base + ct * 16 + col;
                const int jc_n = (jo_n < len) ? (i + 1 + jo_n) : (LL - 1);
                const float p_n = P[(size_t)i * LL + jc_n];
                const float dx = xyz[jc_n * 3 + 0] - xi0;
                const float dy = xyz[jc_n * 3 + 1] - xi1;
                const float dz = xyz[jc_n * 3 + 2] - xi2;
                const float d_n = sqrtf(fmaf(dx, dx, fmaf(dy, dy, fmaf(dz, dz, 1e-12f))));
                const float et = ((jo_n >= 2) && (p_n > THRESH)) ? 1.0f : 0.0f;
                const float pj = (jo_n == 0) ? 1.0f : p_n;

                // B frag: rbf[k = quad*8+j][edge col]
                float r[8];
                #pragma unroll
                for (int j = 0; j < 8; ++j) {
                    const float t0 = d_n - muj[j];
                    r[j] = __expf(t0 * t0 * nis2[j]);
                }
                FragU bf;
                bf.u[0] = pack_bf(r[1], r[0]); bf.u[1] = pack_bf(r[3], r[2]);
                bf.u[2] = pack_bf(r[5], r[4]); bf.u[3] = pack_bf(r[7], r[6]);

                const float* npr = nproj + (size_t)jc_n * MM;
                float g = 0.0f;
                #pragma unroll
                for (int mt = 0; mt < 4; ++mt) {
                    f32x4_t c0 = *(const f32x4_t*)(npr + mt * 16 + quad * 4);
                    // rank-2 part in exact fp32 on the C-init
                    c0[0] = fmaf(et, w0q[mt][0], fmaf(pj, w1q[mt][0], c0[0]));
                    c0[1] = fmaf(et, w0q[mt][1], fmaf(pj, w1q[mt][1], c0[1]));
                    c0[2] = fmaf(et, w0q[mt][2], fmaf(pj, w1q[mt][2], c0[2]));
                    c0[3] = fmaf(et, w0q[mt][3], fmaf(pj, w1q[mt][3], c0[3]));
                    c0 = __builtin_amdgcn_mfma_f32_16x16x32_bf16(ar[mt].v, bf.v, c0, 0, 0, 0);
                    g = fmaf(fmaxf(c0[0], 0.f), wv[mt][0], g);
                    g = fmaf(fmaxf(c0[1], 0.f), wv[mt][1], g);
                    g = fmaf(fmaxf(c0[2], 0.f), wv[mt][2], g);
                    g = fmaf(fmaxf(c0[3], 0.f), wv[mt][3], g);
                }
                // sum quad partials -> every lane holds gdot of edge ct*16+(lane&15)
                g += __shfl_xor(g, 16, 64);
                g += __shfl_xor(g, 32, 64);
                res[ct] = g;
            }
            // lane l's own edge (base+l) lives in res[quad]
            float gd = res[0];
            gd = (quad == 1) ? res[1] : gd;
            gd = (quad == 2) ? res[2] : gd;
            gd = (quad == 3) ? res[3] : gd;
            const float gate = msk ? (1.0f / (1.0f + __expf(-gd))) : 0.0f;
            ax = fmaf(gate, rx, ax);
            ay = fmaf(gate, ry, ay);
            az = fmaf(gate, rz, az);
        }

        // reduce 64 lanes, then 8 waves
        #pragma unroll
        for (int off = 32; off > 0; off >>= 1) {
            ax += __shfl_down(ax, off, 64);
            ay += __shfl_down(ay, off, 64);
            az += __shfl_down(az, off, 64);
        }
        if (lane == 0) {
            sred[wave][0] = ax; sred[wave][1] = ay; sred[wave][2] = az;
        }
        __syncthreads();
        if (tid == 0) {
            float tx = 0.f, ty = 0.f, tz = 0.f;
            #pragma unroll
            for (int w = 0; w < 8; ++w) {
                tx += sred[w][0]; ty += sred[w][1]; tz += sred[w][2];
            }
            out[i * 3 + 0] = xi0 + tx;
            out[i * 3 + 1] = xi1 + ty;
            out[i * 3 + 2] = xi2 + tz;
        }
        __syncthreads();
    }
}

extern "C" void kernel_launch(void* const* d_in, const int* in_sizes, int n_in,
                              void* d_out, int out_size, void* d_ws, size_t ws_size,
                              hipStream_t stream) {
    const float* S         = (const float*)d_in[0];
    const float* P         = (const float*)d_in[1];
    const float* xyz       = (const float*)d_in[2];
    const float* rbf_mu    = (const float*)d_in[3];
    const float* rbf_sigma = (const float*)d_in[4];
    const float* W_edge    = (const float*)d_in[5];
    const float* b_edge    = (const float*)d_in[6];
    const float* W_node    = (const float*)d_in[7];
    const float* w_out     = (const float*)d_in[8];
    float* out = (float*)d_out;
    float* ws  = (float*)d_ws;

    prep_kernel<<<LL / 2 + 1, 256, 0, stream>>>(S, rbf_mu, rbf_sigma, W_edge,
                                                b_edge, W_node, ws);
    edge_kernel<<<LL / 2, 512, 0, stream>>>(P, xyz, w_out, ws, out);
}